// Round 5
// baseline (369.876 us; speedup 1.0000x reference)
//
#include <hip/hip_runtime.h>

// Problem constants
#define T_DIM   100
#define N_NODES 25
#define C_DIM   128
#define B_DIM   64
#define G_TOTAL 6400          // B*T
#define GNV     3200          // N_NODES * C_DIM (per-graph elements)
#define CNT_PER_T 204800.0f   // B * N * C
#define NBLOCKS 800           // G_TOTAL/8: 2 units of 4 graphs per block

// ws float offsets
#define WS_A2P  0             // 1024 bf16 (512 floats): A2 bf16, zero-padded 32x32 [m][k]
#define WS_RS1  640           // 25 floats: rowsum(Ahat)
#define WS_BW   768           // 128 floats: W2^T b1
#define WS_SUM  1024          // 100 floats: per-t sum   (zeroed by k_pre)
#define WS_SSQ  1152          // 100 floats: per-t sumsq (stats[128+t])
#define WS_BAR  1472          // 1 uint: grid barrier counter (zeroed by k_pre)
#define WS_W12T 2048          // 16384 bf16 (= 8192 floats): W12^T, [c][v]

// Y_T layout in LDS: [g][c][row], row-stride 36 shorts (72 B -> 16-bank spread,
// 2-way aliasing free; 8B-aligned).
#define YSTR  36
#define YGSTR (128 * YSTR)    // 4608 shorts per graph

typedef __attribute__((ext_vector_type(8))) short short8;
typedef __attribute__((ext_vector_type(4))) float f32x4;

__device__ __forceinline__ unsigned short f2bf(float f) {
  unsigned int u = __float_as_uint(f);
  u += 0x7FFFu + ((u >> 16) & 1u);   // RNE
  return (unsigned short)(u >> 16);
}
__device__ __forceinline__ unsigned int pack2bf(float a, float b) {
  return (unsigned int)f2bf(a) | ((unsigned int)f2bf(b) << 16);
}
__device__ __forceinline__ float bf_lo(unsigned int p) { return __uint_as_float(p << 16); }
__device__ __forceinline__ float bf_hi(unsigned int p) { return __uint_as_float(p & 0xFFFF0000u); }

// ---------------------------------------------------------------------------
// k_pre: blocks 0..63 = W12T/bw prep; block 64 = adjacency prep + zero stats/bar.
__global__ void k_pre(const int* __restrict__ edge, const float* __restrict__ W1,
                      const float* __restrict__ W2, const float* __restrict__ b1,
                      float* __restrict__ wsf) {
  __shared__ float sA[N_NODES * N_NODES];
  __shared__ float sA2[N_NODES * N_NODES];
  __shared__ float sdeg[N_NODES];
  __shared__ float sdis[N_NODES];
  const int tid = threadIdx.x;  // 256

  if (blockIdx.x < 64) {
    int j = blockIdx.x * 256 + tid;          // 16384
    int c = j & 127, v = j >> 7;
    float acc = 0.f;
#pragma unroll 8
    for (int u = 0; u < 128; u++) acc = fmaf(W1[v * 128 + u], W2[u * 128 + c], acc);
    ((unsigned short*)(wsf + WS_W12T))[c * 128 + v] = f2bf(acc);
    if (j < 128) {
      float a2 = 0.f;
      for (int u = 0; u < 128; u++) a2 = fmaf(W2[u * 128 + j], b1[u], a2);
      wsf[WS_BW + j] = a2;
    }
    return;
  }

  // ---- block 64: normalized adjacency, A2 = Ahat^2 (bf16 padded), rowsums.
  if (tid < N_NODES) sdeg[tid] = 0.f;
  for (int j = tid; j < N_NODES * N_NODES; j += 256) sA[j] = 0.f;
  __syncthreads();
  if (tid < 64) atomicAdd(&sdeg[edge[64 + tid]], 1.f);
  __syncthreads();
  if (tid < N_NODES) sdis[tid] = rsqrtf(sdeg[tid] + 1.f);
  __syncthreads();
  if (tid < 64) {
    int s = edge[tid], tg = edge[64 + tid];
    atomicAdd(&sA[tg * N_NODES + s], sdis[s] * sdis[tg]);
  }
  __syncthreads();
  if (tid < N_NODES) atomicAdd(&sA[tid * N_NODES + tid], sdis[tid] * sdis[tid]);
  __syncthreads();
  for (int j = tid; j < N_NODES * N_NODES; j += 256) {
    int n = j / N_NODES, m = j - n * N_NODES;
    float acc = 0.f;
    for (int k = 0; k < N_NODES; k++) acc = fmaf(sA[n * N_NODES + k], sA[k * N_NODES + m], acc);
    sA2[j] = acc;
  }
  __syncthreads();
  for (int j = tid; j < 1024; j += 256) {
    int m = j >> 5, k = j & 31;
    float v = (m < N_NODES && k < N_NODES) ? sA2[m * N_NODES + k] : 0.f;
    ((unsigned short*)(wsf + WS_A2P))[j] = f2bf(v);
  }
  if (tid < N_NODES) {
    float rs = 0.f;
    for (int m = 0; m < N_NODES; m++) rs += sA[tid * N_NODES + m];
    wsf[WS_RS1 + tid] = rs;
  }
  if (tid < T_DIM) { wsf[WS_SUM + tid] = 0.f; wsf[WS_SSQ - WS_SUM + WS_SUM + tid] = 0.f; }
  if (tid < T_DIM) wsf[WS_SSQ + tid] = 0.f;
  if (tid == 0) *(unsigned int*)(wsf + WS_BAR) = 0u;
}

// ---------------------------------------------------------------------------
// k_main: 800 blocks, 2 units each (unit = 4 graphs, same t). Plain launch;
// grid-wide sync via ws atomic counter (all 800 blocks co-resident: 4/CU
// from __launch_bounds__(256,4) + 38KB LDS -> capacity 1024 >= 800).
//   Phase 1 per unit: X->LDS(bf16) -> MFMA Y=X*W12 -> Y_T LDS ->
//                     MFMA H=A2*Y -> +bias -> H packed bf16 in regs + stats.
//   barrier (device-scope atomics)
//   Phase 2: atomic-load stats, normalize register H, single out write.
__global__ __launch_bounds__(256, 4) void k_main(const float* __restrict__ x,
                                                 const float* __restrict__ b2,
                                                 const float* __restrict__ wsc,
                                                 float* __restrict__ stats,
                                                 float* __restrict__ out,
                                                 const float* __restrict__ gamma,
                                                 const float* __restrict__ beta) {
  __shared__ __align__(16) unsigned short LB[4 * YGSTR];  // 36864 B union
  __shared__ float sBW[128];
  __shared__ float sB2[128];
  __shared__ float rs1[32];
  __shared__ float red[8];
  const int tid = threadIdx.x;
  const int bid = blockIdx.x;
  const int wv = tid >> 6, lane = tid & 63, quad = lane >> 4, l16 = lane & 15;

  if (tid < 128) {
    sBW[tid] = wsc[WS_BW + tid];
    if (tid < 32) rs1[tid] = (tid < N_NODES) ? wsc[WS_RS1 + tid] : 0.f;
  } else {
    sB2[tid - 128] = b2[tid - 128];
  }

  // W12T B-fragments (shared by both units), straight from global (L2-hot).
  short8 bfr[2][4];
  {
    const unsigned short* Wg = (const unsigned short*)(wsc + WS_W12T);
#pragma unroll
    for (int nt = 0; nt < 2; nt++) {
      const short8* rp = (const short8*)&Wg[(wv * 32 + nt * 16 + l16) * 128];
#pragma unroll
      for (int ks = 0; ks < 4; ks++) bfr[nt][ks] = rp[(ks << 2) | quad];
    }
  }
  // A2 fragments (stage 2), shared by both units.
  const unsigned short* A2p = (const unsigned short*)(wsc + WS_A2P);
  short8 a2f[2];
#pragma unroll
  for (int mt2 = 0; mt2 < 2; mt2++)
    a2f[mt2] = *(const short8*)&A2p[(mt2 * 16 + l16) * 32 + quad * 8];

  unsigned int Hp[2][32];  // packed bf16 H: [unit][((half*2+mt2)*4+nt)*2 + pair]

#pragma unroll
  for (int u = 0; u < 2; u++) {
    const int unit = bid * 2 + u;
    const int t = unit % T_DIM;
    const int bq = unit / T_DIM;

    __syncthreads();  // LB / red reuse fence

    // zero X pad rows (3 per graph: g*28+25..27)
    for (int j = tid; j < 12 * 128; j += 256) {
      int pr = j >> 7;
      int g = pr / 3, rr = pr - g * 3;
      LB[(g * 28 + 25 + rr) * 128 + (j & 127)] = 0;
    }
    // Load X (fp32), convert bf16, store to X view (swizzled by row&15).
    {
      const int v = tid & 127;
      const int gl0 = tid >> 7;
      const int g0 = (bq * 4 + gl0) * T_DIM + t;
      const float* xp0 = x + g0 * GNV + v;
      const float* xp1 = xp0 + 2 * T_DIM * GNV;
      float x0[25], x1[25];
#pragma unroll
      for (int m = 0; m < 25; m++) { x0[m] = xp0[m * 128]; x1[m] = xp1[m * 128]; }
#pragma unroll
      for (int n = 0; n < 25; n++) {
        int r0 = gl0 * 28 + n, r1 = (gl0 + 2) * 28 + n;
        LB[r0 * 128 + (v ^ ((r0 & 15) << 3))] = f2bf(x0[n]);
        LB[r1 * 128 + (v ^ ((r1 & 15) << 3))] = f2bf(x1[n]);
      }
    }
    __syncthreads();

    // ---- Stage 1: Y = X * W12. Wave wv covers c in [wv*32, +32). 56 MFMA.
    f32x4 acc[7][2];
#pragma unroll
    for (int mt = 0; mt < 7; mt++)
#pragma unroll
      for (int nt = 0; nt < 2; nt++)
#pragma unroll
        for (int r = 0; r < 4; r++) acc[mt][nt][r] = 0.f;

#pragma unroll
    for (int ks = 0; ks < 4; ks++) {
      const int cc = (ks << 2) | quad;
#pragma unroll
      for (int mt = 0; mt < 7; mt++) {
        int arow = mt * 16 + l16;
        short8 afr = *(const short8*)&LB[arow * 128 + ((cc ^ (arow & 15)) << 3)];
#pragma unroll
        for (int nt = 0; nt < 2; nt++)
          acc[mt][nt] = __builtin_amdgcn_mfma_f32_16x16x32_bf16(afr, bfr[nt][ks], acc[mt][nt], 0, 0, 0);
      }
    }
    __syncthreads();  // X reads done; LB becomes Y_T

    // Write Y -> Y_T (bf16).
#pragma unroll
    for (int mt = 0; mt < 7; mt++) {
      int row0 = mt * 16 + quad * 4;
      int g = row0 / 28;
      int rl = row0 - g * 28;
#pragma unroll
      for (int nt = 0; nt < 2; nt++) {
        int c = wv * 32 + nt * 16 + l16;
        uint2 p;
        p.x = pack2bf(acc[mt][nt][0], acc[mt][nt][1]);
        p.y = pack2bf(acc[mt][nt][2], acc[mt][nt][3]);
        *(uint2*)&LB[g * YGSTR + c * YSTR + rl] = p;
      }
    }
    {
      uint2 z; z.x = 0u; z.y = 0u;
      for (int j = tid; j < 512; j += 256) {
        int g = j >> 7, c = j & 127;
        *(uint2*)&LB[g * YGSTR + c * YSTR + 28] = z;
      }
    }
    __syncthreads();

    // ---- Stage 2: H_g = A2 * Y_g. Wave wv <-> graph wv. 16 MFMA.
    float sum = 0.f, ssq = 0.f;
#pragma unroll
    for (int half = 0; half < 2; half++) {
      f32x4 acc2[2][4];
#pragma unroll
      for (int mt2 = 0; mt2 < 2; mt2++)
#pragma unroll
        for (int nt = 0; nt < 4; nt++)
#pragma unroll
          for (int r = 0; r < 4; r++) acc2[mt2][nt][r] = 0.f;

#pragma unroll
      for (int nt = 0; nt < 4; nt++) {
        int c = (half * 4 + nt) * 16 + l16;
        int base = wv * YGSTR + c * YSTR + quad * 8;
        uint2 lo = *(const uint2*)&LB[base];
        uint2 hi = *(const uint2*)&LB[base + 4];
        uint4 w; w.x = lo.x; w.y = lo.y; w.z = hi.x; w.w = hi.y;
        short8 bf = __builtin_bit_cast(short8, w);
#pragma unroll
        for (int mt2 = 0; mt2 < 2; mt2++)
          acc2[mt2][nt] = __builtin_amdgcn_mfma_f32_16x16x32_bf16(a2f[mt2], bf, acc2[mt2][nt], 0, 0, 0);
      }
      // bias + stats + pack to bf16 regs (no global store here).
#pragma unroll
      for (int mt2 = 0; mt2 < 2; mt2++) {
#pragma unroll
        for (int nt = 0; nt < 4; nt++) {
          int c = (half * 4 + nt) * 16 + l16;
          float bw = sBW[c], bb = sB2[c];
          float v[4];
#pragma unroll
          for (int r = 0; r < 4; r++) {
            int m = mt2 * 16 + quad * 4 + r;
            v[r] = acc2[mt2][nt][r] + rs1[m & 31] * bw + bb;
            if (m < N_NODES) { sum += v[r]; ssq += v[r] * v[r]; }
          }
          int bi = ((half * 2 + mt2) * 4 + nt) * 2;
          Hp[u][bi]     = pack2bf(v[0], v[1]);
          Hp[u][bi + 1] = pack2bf(v[2], v[3]);
        }
      }
    }

#pragma unroll
    for (int off = 32; off > 0; off >>= 1) {
      sum += __shfl_down(sum, off, 64);
      ssq += __shfl_down(ssq, off, 64);
    }
    if (lane == 0) { red[wv] = sum; red[4 + wv] = ssq; }
    __syncthreads();
    if (tid == 0) {
      atomicAdd(&stats[t], red[0] + red[1] + red[2] + red[3]);      // device-scope
      atomicAdd(&stats[128 + t], red[4] + red[5] + red[6] + red[7]);
    }
  }

  // ---- Grid barrier: all 800 blocks co-resident by construction.
  {
    unsigned int* bar = (unsigned int*)(stats + (WS_BAR - WS_SUM));
    __syncthreads();
    if (tid == 0) {
      __hip_atomic_fetch_add(bar, 1u, __ATOMIC_ACQ_REL, __HIP_MEMORY_SCOPE_AGENT);
      while (__hip_atomic_load(bar, __ATOMIC_ACQUIRE, __HIP_MEMORY_SCOPE_AGENT) < NBLOCKS)
        __builtin_amdgcn_s_sleep(2);
    }
    __syncthreads();
  }

  // ---- Phase 2: read stats coherently, normalize register H, write out.
  // Atomic loads (AGENT scope): plain loads could hit a stale per-XCD L2 line.
  {
    const int t0 = (bid * 2) % T_DIM;
    const int t1 = (bid * 2 + 1) % T_DIM;
    if (tid == 0) {
      red[0] = __hip_atomic_load(&stats[t0],       __ATOMIC_RELAXED, __HIP_MEMORY_SCOPE_AGENT);
      red[1] = __hip_atomic_load(&stats[128 + t0], __ATOMIC_RELAXED, __HIP_MEMORY_SCOPE_AGENT);
      red[2] = __hip_atomic_load(&stats[t1],       __ATOMIC_RELAXED, __HIP_MEMORY_SCOPE_AGENT);
      red[3] = __hip_atomic_load(&stats[128 + t1], __ATOMIC_RELAXED, __HIP_MEMORY_SCOPE_AGENT);
    }
    __syncthreads();
  }

  const float inv = 1.f / CNT_PER_T;
#pragma unroll
  for (int u = 0; u < 2; u++) {
    const int unit = bid * 2 + u;
    const int t = unit % T_DIM;
    const int bq = unit / T_DIM;
    float s = red[u * 2], q = red[u * 2 + 1];
    float mean = s * inv;
    float var = fmaf(q, inv, -mean * mean);
    float rstd = rsqrtf(var + 1e-5f);
    float gg = gamma[t] * rstd;
    float bbb = fmaf(-mean, gg, beta[t]);
    const int obase = ((bq * 4 + wv) * T_DIM + t) * GNV;
#pragma unroll
    for (int half = 0; half < 2; half++) {
#pragma unroll
      for (int mt2 = 0; mt2 < 2; mt2++) {
#pragma unroll
        for (int nt = 0; nt < 4; nt++) {
          int c = (half * 4 + nt) * 16 + l16;
          int bi = ((half * 2 + mt2) * 4 + nt) * 2;
          float v[4];
          v[0] = bf_lo(Hp[u][bi]);     v[1] = bf_hi(Hp[u][bi]);
          v[2] = bf_lo(Hp[u][bi + 1]); v[3] = bf_hi(Hp[u][bi + 1]);
#pragma unroll
          for (int r = 0; r < 4; r++) {
            int m = mt2 * 16 + quad * 4 + r;
            if (m < N_NODES)
              out[obase + m * 128 + c] = fmaxf(fmaf(v[r], gg, bbb), 0.f);
          }
        }
      }
    }
  }
}

// ---------------------------------------------------------------------------
extern "C" void kernel_launch(void* const* d_in, const int* in_sizes, int n_in,
                              void* d_out, int out_size, void* d_ws, size_t ws_size,
                              hipStream_t stream) {
  const float* x     = (const float*)d_in[0];
  const int*   edge  = (const int*)d_in[1];
  const float* W1    = (const float*)d_in[2];
  const float* b1    = (const float*)d_in[3];
  const float* W2    = (const float*)d_in[4];
  const float* b2    = (const float*)d_in[5];
  const float* gamma = (const float*)d_in[6];
  const float* beta  = (const float*)d_in[7];
  float* out = (float*)d_out;
  float* wsf = (float*)d_ws;
  float* stats = wsf + WS_SUM;

  k_pre<<<65, 256, 0, stream>>>(edge, W1, W2, b1, wsf);
  k_main<<<NBLOCKS, 256, 0, stream>>>(x, b2, wsf, stats, out, gamma, beta);
}